// Round 1
// baseline (207.000 us; speedup 1.0000x reference)
//
#include <hip/hip_runtime.h>
#include <hip/hip_bf16.h>
#include <cstdint>

using bf16 = __hip_bfloat16;
typedef __attribute__((ext_vector_type(8))) short s8v;
typedef __attribute__((ext_vector_type(4))) float f32x4;

#define DEV static __device__ __forceinline__

DEV float b2f(unsigned short u) {
    union { float f; unsigned int i; } w; w.i = ((unsigned int)u) << 16; return w.f;
}
DEV unsigned short f2b(float x) {
    __hip_bfloat16 h = __float2bfloat16(x);
    return __builtin_bit_cast(unsigned short, h);
}
DEV float sigm(float x) { return 1.0f / (1.0f + __expf(-x)); }

DEV void gload16(const void* g, void* l) {
    __builtin_amdgcn_global_load_lds(
        (const __attribute__((address_space(1))) uint32_t*)g,
        (__attribute__((address_space(3))) uint32_t*)l, 16, 0, 0);
}

// ---------------------------------------------------------------------------
// Generic bf16 GEMM, C = A (MxK, row-major) * B^T (B is NxK row-major).
// 128x128 tile, BK=64, 4 waves (2x2), 16x16x32 bf16 MFMA. Epilogue by EPI:
//  0: bf16 out = sigmoid(acc)
//  1: bf16 out = mask[row] ? d[row]*(acc + d[row]*Xres[row,col]) : 0   (agg)
//  2: bf16 out = relu(acc + bias[col])
//  3: bf16 out = acc + bias[col]
//  4: f32  out = (mask[row]&mask[col]) ? sigmoid(acc) : 0
// ---------------------------------------------------------------------------
template<int EPI>
__global__ __launch_bounds__(256)
void gemm_bt(const bf16* __restrict__ A, const bf16* __restrict__ B,
             void* __restrict__ C, const int M, const int N, const int K,
             const size_t sA, const size_t sB, const size_t sC,
             const float* __restrict__ Xres, const float* __restrict__ dval,
             const int* __restrict__ mask, const float* __restrict__ bias)
{
    __shared__ bf16 As[128 * 64];
    __shared__ bf16 Bs[128 * 64];
    const int b = blockIdx.z;
    const bf16* Ab = A + (size_t)b * sA;
    const bf16* Bb = B + (size_t)b * sB;
    const int bm = blockIdx.x * 128;
    const int bn = blockIdx.y * 128;
    const int tid = threadIdx.x;
    const int lane = tid & 63;
    const int wv = tid >> 6;
    const int wr = wv >> 1, wc = wv & 1;
    const int fr = lane & 15, fq = lane >> 4;

    f32x4 acc[4][4];
#pragma unroll
    for (int m = 0; m < 4; ++m)
#pragma unroll
        for (int n = 0; n < 4; ++n)
            acc[m][n] = (f32x4){0.f, 0.f, 0.f, 0.f};

    const size_t lda = (size_t)K * 2;  // row stride in bytes

    for (int k0 = 0; k0 < K; k0 += 64) {
        __syncthreads();
        const size_t kb = (size_t)k0 * 2;
#pragma unroll
        for (int i = 0; i < 4; ++i) {
            const int ldsOff = i * 4096 + wv * 1024;   // wave-uniform LDS byte base
            const int myOff = ldsOff + lane * 16;      // this lane's slot
            const int row = myOff >> 7;                // 128B per tile row (64 bf16)
            const int colb = myOff & 127;
            gload16((const char*)Ab + (size_t)(bm + row) * lda + kb + colb,
                    (char*)As + ldsOff);
            gload16((const char*)Bb + (size_t)(bn + row) * lda + kb + colb,
                    (char*)Bs + ldsOff);
        }
        __syncthreads();
#pragma unroll
        for (int kk = 0; kk < 2; ++kk) {
            s8v af[4], bf_[4];
#pragma unroll
            for (int m = 0; m < 4; ++m)
                af[m] = *(const s8v*)&As[(wr * 64 + m * 16 + fr) * 64 + kk * 32 + fq * 8];
#pragma unroll
            for (int n = 0; n < 4; ++n)
                bf_[n] = *(const s8v*)&Bs[(wc * 64 + n * 16 + fr) * 64 + kk * 32 + fq * 8];
#pragma unroll
            for (int m = 0; m < 4; ++m)
#pragma unroll
                for (int n = 0; n < 4; ++n)
                    acc[m][n] = __builtin_amdgcn_mfma_f32_16x16x32_bf16(
                        af[m], bf_[n], acc[m][n], 0, 0, 0);
        }
    }

    // epilogue: C/D layout col = lane&15, row = (lane>>4)*4 + reg
    const int row0 = bm + wr * 64 + fq * 4;
    const int col0 = bn + wc * 64 + fr;
#pragma unroll
    for (int m = 0; m < 4; ++m) {
#pragma unroll
        for (int n = 0; n < 4; ++n) {
            const int col = col0 + n * 16;
#pragma unroll
            for (int r = 0; r < 4; ++r) {
                const int row = row0 + m * 16 + r;
                const float x = acc[m][n][r];
                const size_t cidx = (size_t)b * sC + (size_t)row * N + col;
                if constexpr (EPI == 0) {
                    ((bf16*)C)[cidx] = __float2bfloat16(sigm(x));
                } else if constexpr (EPI == 1) {
                    const float dn = dval[(size_t)b * M + row];
                    const int mn = mask[(size_t)b * M + row];
                    const float xv = Xres[(size_t)b * M * N + (size_t)row * N + col];
                    ((bf16*)C)[cidx] = __float2bfloat16(mn ? dn * (x + dn * xv) : 0.0f);
                } else if constexpr (EPI == 2) {
                    ((bf16*)C)[cidx] = __float2bfloat16(fmaxf(x + bias[col], 0.0f));
                } else if constexpr (EPI == 3) {
                    ((bf16*)C)[cidx] = __float2bfloat16(x + bias[col]);
                } else {
                    const int mr = mask[(size_t)b * M + row];
                    const int mc = mask[(size_t)b * M + col];
                    ((float*)C)[cidx] = (mr & mc) ? sigm(x) : 0.0f;
                }
            }
        }
    }
}

// ---------------------------------------------------------------------------
// Row-normalize X (f32 [B*N,256]) -> Xn (bf16). One wave per row.
// ---------------------------------------------------------------------------
__global__ __launch_bounds__(256)
void xn_kernel(const float* __restrict__ X, bf16* __restrict__ Xn)
{
    const int lane = threadIdx.x & 63;
    const size_t row = (size_t)blockIdx.x * 4 + (threadIdx.x >> 6);
    const float4 v = *(const float4*)&X[row * 256 + lane * 4];
    float ss = v.x * v.x + v.y * v.y + v.z * v.z + v.w * v.w;
#pragma unroll
    for (int o = 32; o; o >>= 1) ss += __shfl_xor(ss, o);
    const float inv = 1.0f / fmaxf(sqrtf(ss), 1e-12f);
    ushort4 o4;
    o4.x = f2b(v.x * inv); o4.y = f2b(v.y * inv);
    o4.z = f2b(v.z * inv); o4.w = f2b(v.w * inv);
    *(ushort4*)&Xn[row * 256 + lane * 4] = o4;
}

// ---------------------------------------------------------------------------
// deg_n = m_n * (sum_m S[n,m]*m_m + 1) ; dval = rsqrt(max(deg,1e-6)).
// One block per (n, b) row of S.
// ---------------------------------------------------------------------------
__global__ __launch_bounds__(256)
void rowsum_kernel(const bf16* __restrict__ S, const int* __restrict__ mask,
                   float* __restrict__ dval)
{
    const int n = blockIdx.x, b = blockIdx.y;
    const bf16* row = S + ((size_t)b * 2048 + n) * 2048;
    const int* mb = mask + (size_t)b * 2048;
    const int t = threadIdx.x;
    const int base = t * 8;
    const s8v sv = *(const s8v*)&row[base];
    const int4 mk0 = *(const int4*)&mb[base];
    const int4 mk1 = *(const int4*)&mb[base + 4];
    float s = 0.f;
    s += mk0.x ? b2f((unsigned short)sv[0]) : 0.f;
    s += mk0.y ? b2f((unsigned short)sv[1]) : 0.f;
    s += mk0.z ? b2f((unsigned short)sv[2]) : 0.f;
    s += mk0.w ? b2f((unsigned short)sv[3]) : 0.f;
    s += mk1.x ? b2f((unsigned short)sv[4]) : 0.f;
    s += mk1.y ? b2f((unsigned short)sv[5]) : 0.f;
    s += mk1.z ? b2f((unsigned short)sv[6]) : 0.f;
    s += mk1.w ? b2f((unsigned short)sv[7]) : 0.f;
#pragma unroll
    for (int o = 32; o; o >>= 1) s += __shfl_xor(s, o);
    __shared__ float red[4];
    if ((t & 63) == 0) red[t >> 6] = s;
    __syncthreads();
    if (t == 0) {
        const float tot = red[0] + red[1] + red[2] + red[3];
        const float deg = mb[n] ? (tot + 1.0f) : 0.0f;
        dval[(size_t)b * 2048 + n] = rsqrtf(fmaxf(deg, 1e-6f));
    }
}

// ---------------------------------------------------------------------------
// Yt[b][d][m] = bf16( (mask[m] ? dval[m] : 0) * X[b][m][d] )  (64x64 LDS transpose)
// ---------------------------------------------------------------------------
__global__ __launch_bounds__(256)
void yt_kernel(const float* __restrict__ X, const float* __restrict__ dval,
               const int* __restrict__ mask, bf16* __restrict__ Yt)
{
    __shared__ float tile[64][65];
    const int b = blockIdx.z;
    const int m0 = blockIdx.x * 64, d0 = blockIdx.y * 64;
    const float* Xb = X + (size_t)b * 2048 * 256;
    const float* dv = dval + (size_t)b * 2048;
    const int* mk = mask + (size_t)b * 2048;
    const int t = threadIdx.x;
    const int ml = t >> 4;
    const int dl4 = (t & 15) * 4;
#pragma unroll
    for (int i = 0; i < 4; ++i) {
        const int m = ml + i * 16;
        const int gm = m0 + m;
        const float sd = mk[gm] ? dv[gm] : 0.0f;
        const float4 v = *(const float4*)&Xb[(size_t)gm * 256 + d0 + dl4];
        tile[m][dl4 + 0] = v.x * sd; tile[m][dl4 + 1] = v.y * sd;
        tile[m][dl4 + 2] = v.z * sd; tile[m][dl4 + 3] = v.w * sd;
    }
    __syncthreads();
    bf16* Yb = Yt + (size_t)b * 256 * 2048;
    const int dl = t >> 4;
    const int ml4 = (t & 15) * 4;
#pragma unroll
    for (int i = 0; i < 4; ++i) {
        const int d = dl + i * 16;
        ushort4 o;
        o.x = f2b(tile[ml4 + 0][d]);
        o.y = f2b(tile[ml4 + 1][d]);
        o.z = f2b(tile[ml4 + 2][d]);
        o.w = f2b(tile[ml4 + 3][d]);
        *(ushort4*)&Yb[(size_t)(d0 + d) * 2048 + m0 + ml4] = o;
    }
}

// ---------------------------------------------------------------------------
// Transpose both weight matrices to bf16: Wt[h][d] = bf16(W[d][h]).
// ---------------------------------------------------------------------------
__global__ __launch_bounds__(256)
void prep_w(const float* __restrict__ W1, const float* __restrict__ W2,
            bf16* __restrict__ W1t, bf16* __restrict__ W2t)
{
    const int idx = blockIdx.x * 256 + threadIdx.x;
    const int h = idx & 255, d = idx >> 8;
    W1t[h * 256 + d] = __float2bfloat16(W1[idx]);
    W2t[h * 256 + d] = __float2bfloat16(W2[idx]);
}

extern "C" void kernel_launch(void* const* d_in, const int* in_sizes, int n_in,
                              void* d_out, int out_size, void* d_ws, size_t ws_size,
                              hipStream_t stream)
{
    (void)in_sizes; (void)n_in; (void)out_size; (void)ws_size;
    const float* X  = (const float*)d_in[0];
    const int*  msk = (const int*)d_in[1];
    const float* W1 = (const float*)d_in[2];
    const float* b1 = (const float*)d_in[3];
    const float* W2 = (const float*)d_in[4];
    const float* b2 = (const float*)d_in[5];

    // scratch layout inside d_out (134,217,728 B), all dead before final GEMM:
    char* O = (char*)d_out;
    bf16* S    = (bf16*)(O);                 // 67,108,864 B  [8][2048][2048]
    bf16* Xn   = (bf16*)(O + 67108864);      //  8,388,608 B  [8][2048][256]
    bf16* Yt   = (bf16*)(O + 75497472);      //  8,388,608 B  [8][256][2048]
    bf16* agg  = (bf16*)(O + 83886080);      //  8,388,608 B  [8][2048][256]
    bf16* Hf   = (bf16*)(O + 92274688);      //  8,388,608 B  [16384][256]
    float* dvl = (float*)(O + 100663296);    //     65,536 B  [8][2048]
    bf16* W1t  = (bf16*)(O + 100728832);     //    131,072 B
    bf16* W2t  = (bf16*)(O + 100859904);     //    131,072 B
    bf16* P    = (bf16*)d_ws;                //  8,388,608 B  [16384][256] (must survive final GEMM)

    prep_w<<<256, 256, 0, stream>>>(W1, W2, W1t, W2t);
    xn_kernel<<<4096, 256, 0, stream>>>(X, Xn);

    // S = sigmoid(Xn Xn^T), bf16
    gemm_bt<0><<<dim3(16, 16, 8), 256, 0, stream>>>(
        Xn, Xn, S, 2048, 2048, 256,
        (size_t)2048 * 256, (size_t)2048 * 256, (size_t)2048 * 2048,
        nullptr, nullptr, nullptr, nullptr);

    rowsum_kernel<<<dim3(2048, 8), 256, 0, stream>>>(S, msk, dvl);
    yt_kernel<<<dim3(32, 4, 8), 256, 0, stream>>>(X, dvl, msk, Yt);

    // agg = m d (S @ Y + d X), bf16
    gemm_bt<1><<<dim3(16, 2, 8), 256, 0, stream>>>(
        S, Yt, agg, 2048, 256, 2048,
        (size_t)2048 * 2048, (size_t)256 * 2048, (size_t)2048 * 256,
        X, dvl, msk, nullptr);

    // Hf = relu(agg @ W1 + b1)
    gemm_bt<2><<<dim3(128, 2, 1), 256, 0, stream>>>(
        agg, W1t, Hf, 16384, 256, 256, 0, 0, 0,
        nullptr, nullptr, nullptr, b1);

    // P = Hf @ W2 + b2
    gemm_bt<3><<<dim3(128, 2, 1), 256, 0, stream>>>(
        Hf, W2t, P, 16384, 256, 256, 0, 0, 0,
        nullptr, nullptr, nullptr, b2);

    // out = mask_r * mask_c * sigmoid(P P^T), f32 (overwrites all scratch in d_out)
    gemm_bt<4><<<dim3(16, 16, 8), 256, 0, stream>>>(
        P, P, d_out, 2048, 2048, 256,
        (size_t)2048 * 256, (size_t)2048 * 256, (size_t)2048 * 2048,
        nullptr, nullptr, msk, nullptr);
}

// Round 2
// 172.159 us; speedup vs baseline: 1.2024x; 1.2024x over previous
//
#include <hip/hip_runtime.h>
#include <hip/hip_bf16.h>
#include <cstdint>

using bf16 = __hip_bfloat16;
typedef __attribute__((ext_vector_type(8))) short s8v;
typedef __attribute__((ext_vector_type(4))) float f32x4;

#define DEV static __device__ __forceinline__

DEV float b2f(unsigned short u) {
    union { float f; unsigned int i; } w; w.i = ((unsigned int)u) << 16; return w.f;
}
DEV unsigned short f2b(float x) {
    __hip_bfloat16 h = __float2bfloat16(x);
    return __builtin_bit_cast(unsigned short, h);
}
DEV float sigm(float x) { return 1.0f / (1.0f + __expf(-x)); }

DEV void gload16(const void* g, void* l) {
    __builtin_amdgcn_global_load_lds(
        (const __attribute__((address_space(1))) uint32_t*)g,
        (__attribute__((address_space(3))) uint32_t*)l, 16, 0, 0);
}

// ---------------------------------------------------------------------------
// Generic bf16 GEMM, C = A (MxK, row-major) * B^T (B is NxK row-major).
// 128x128 tile, BK=64, 4 waves (2x2), 16x16x32 bf16 MFMA.
// 2-phase double-buffered LDS (stage next tile before computing current),
// XOR-swizzled LDS layout (phys_byte = logical ^ ((row&7)<<4)) applied via
// inverse-swizzled GLOBAL source (gload_lds dest stays linear) + swizzled
// ds_read addresses -> 16-way bank conflict becomes 2-way (free).
// Epilogue by EPI:
//  0: bf16 out = sigmoid(acc)
//  1: bf16 out = mask[row] ? d[row]*(acc + d[row]*Xres[row,col]) : 0   (agg)
//  2: bf16 out = relu(acc + bias[col])
//  3: bf16 out = acc + bias[col]
//  4: f32  out = (mask[row]&mask[col]) ? sigmoid(acc) : 0
// ---------------------------------------------------------------------------
template<int EPI>
__global__ __launch_bounds__(256)
void gemm_bt(const bf16* __restrict__ A, const bf16* __restrict__ B,
             void* __restrict__ C, const int M, const int N, const int K,
             const size_t sA, const size_t sB, const size_t sC,
             const float* __restrict__ Xres, const float* __restrict__ dval,
             const int* __restrict__ mask, const float* __restrict__ bias)
{
    // [buf][A/B][128 rows][64 bf16] ; buf stride 32768 B, A/B stride 16384 B
    __shared__ bf16 sm[2][2][128 * 64];
    const int b = blockIdx.z;
    const char* Ab = (const char*)(A + (size_t)b * sA);
    const char* Bb = (const char*)(B + (size_t)b * sB);
    const int bm = blockIdx.x * 128;
    const int bn = blockIdx.y * 128;
    const int tid = threadIdx.x;
    const int lane = tid & 63;
    const int wv = tid >> 6;
    const int wr = wv >> 1, wc = wv & 1;
    const int fr = lane & 15, fq = lane >> 4;
    const size_t lda = (size_t)K * 2;  // row stride in bytes

    // Loop-invariant staging offsets. Linear LDS dest slot -> logical source:
    // row = physOff>>7 (XOR stays within the 128B row), logical col byte =
    // (physOff&127) ^ ((row&7)<<4).
    size_t aOff[4], bOff[4];
    int ldsO[4];
#pragma unroll
    for (int i = 0; i < 4; ++i) {
        const int ldsOff = i * 4096 + wv * 1024;  // wave-uniform LDS byte base
        const int myOff = ldsOff + lane * 16;     // this lane's slot
        const int row = myOff >> 7;
        const int lc = (myOff & 127) ^ ((row & 7) << 4);
        ldsO[i] = ldsOff;
        aOff[i] = (size_t)(bm + row) * lda + lc;
        bOff[i] = (size_t)(bn + row) * lda + lc;
    }

    f32x4 acc[4][4];
#pragma unroll
    for (int m = 0; m < 4; ++m)
#pragma unroll
        for (int n = 0; n < 4; ++n)
            acc[m][n] = (f32x4){0.f, 0.f, 0.f, 0.f};

    char* smb = (char*)&sm[0][0][0];

    auto STAGE = [&](int buf, size_t kb) {
#pragma unroll
        for (int i = 0; i < 4; ++i) {
            gload16(Ab + aOff[i] + kb, smb + buf * 32768 + ldsO[i]);
            gload16(Bb + bOff[i] + kb, smb + buf * 32768 + 16384 + ldsO[i]);
        }
    };

    auto COMPUTE = [&](int buf) {
#pragma unroll
        for (int kk = 0; kk < 2; ++kk) {
            s8v af[4], bfv[4];
#pragma unroll
            for (int m = 0; m < 4; ++m) {
                const int r = wr * 64 + m * 16 + fr;
                const int pb = (r << 7) | ((kk * 64 + fq * 16) ^ ((r & 7) << 4));
                af[m] = *(const s8v*)(smb + buf * 32768 + pb);
            }
#pragma unroll
            for (int n = 0; n < 4; ++n) {
                const int r = wc * 64 + n * 16 + fr;
                const int pb = (r << 7) | ((kk * 64 + fq * 16) ^ ((r & 7) << 4));
                bfv[n] = *(const s8v*)(smb + buf * 32768 + 16384 + pb);
            }
#pragma unroll
            for (int m = 0; m < 4; ++m)
#pragma unroll
                for (int n = 0; n < 4; ++n)
                    acc[m][n] = __builtin_amdgcn_mfma_f32_16x16x32_bf16(
                        af[m], bfv[n], acc[m][n], 0, 0, 0);
        }
    };

    const int NT = K >> 6;
    STAGE(0, 0);
    asm volatile("s_waitcnt vmcnt(0)" ::: "memory");
    __syncthreads();
    int cur = 0;
    for (int t = 0; t < NT - 1; ++t) {
        STAGE(cur ^ 1, (size_t)(t + 1) * 128);  // 64 bf16 = 128 bytes of K
        COMPUTE(cur);
        asm volatile("s_waitcnt vmcnt(0)" ::: "memory");
        __syncthreads();
        cur ^= 1;
    }
    COMPUTE(cur);

    // epilogue: C/D layout col = lane&15, row = (lane>>4)*4 + reg
    const int row0 = bm + wr * 64 + fq * 4;
    const int col0 = bn + wc * 64 + fr;
#pragma unroll
    for (int m = 0; m < 4; ++m) {
#pragma unroll
        for (int n = 0; n < 4; ++n) {
            const int col = col0 + n * 16;
#pragma unroll
            for (int r = 0; r < 4; ++r) {
                const int row = row0 + m * 16 + r;
                const float x = acc[m][n][r];
                const size_t cidx = (size_t)b * sC + (size_t)row * N + col;
                if constexpr (EPI == 0) {
                    ((bf16*)C)[cidx] = __float2bfloat16(sigm(x));
                } else if constexpr (EPI == 1) {
                    const float dn = dval[(size_t)b * M + row];
                    const int mn = mask[(size_t)b * M + row];
                    const float xv = Xres[(size_t)b * M * N + (size_t)row * N + col];
                    ((bf16*)C)[cidx] = __float2bfloat16(mn ? dn * (x + dn * xv) : 0.0f);
                } else if constexpr (EPI == 2) {
                    ((bf16*)C)[cidx] = __float2bfloat16(fmaxf(x + bias[col], 0.0f));
                } else if constexpr (EPI == 3) {
                    ((bf16*)C)[cidx] = __float2bfloat16(x + bias[col]);
                } else {
                    const int mr = mask[(size_t)b * M + row];
                    const int mc = mask[(size_t)b * M + col];
                    ((float*)C)[cidx] = (mr & mc) ? sigm(x) : 0.0f;
                }
            }
        }
    }
}

// ---------------------------------------------------------------------------
// Row-normalize X (f32 [B*N,256]) -> Xn (bf16). One wave per row.
// ---------------------------------------------------------------------------
__global__ __launch_bounds__(256)
void xn_kernel(const float* __restrict__ X, bf16* __restrict__ Xn)
{
    const int lane = threadIdx.x & 63;
    const size_t row = (size_t)blockIdx.x * 4 + (threadIdx.x >> 6);
    const float4 v = *(const float4*)&X[row * 256 + lane * 4];
    float ss = v.x * v.x + v.y * v.y + v.z * v.z + v.w * v.w;
#pragma unroll
    for (int o = 32; o; o >>= 1) ss += __shfl_xor(ss, o);
    const float inv = 1.0f / fmaxf(sqrtf(ss), 1e-12f);
    ushort4 o4;
    o4.x = f2b(v.x * inv); o4.y = f2b(v.y * inv);
    o4.z = f2b(v.z * inv); o4.w = f2b(v.w * inv);
    *(ushort4*)&Xn[row * 256 + lane * 4] = o4;
}

// ---------------------------------------------------------------------------
// deg_n = m_n * (sum_m S[n,m]*m_m + 1) ; dval = rsqrt(max(deg,1e-6)).
// One block per (n, b) row of S.
// ---------------------------------------------------------------------------
__global__ __launch_bounds__(256)
void rowsum_kernel(const bf16* __restrict__ S, const int* __restrict__ mask,
                   float* __restrict__ dval)
{
    const int n = blockIdx.x, b = blockIdx.y;
    const bf16* row = S + ((size_t)b * 2048 + n) * 2048;
    const int* mb = mask + (size_t)b * 2048;
    const int t = threadIdx.x;
    const int base = t * 8;
    const s8v sv = *(const s8v*)&row[base];
    const int4 mk0 = *(const int4*)&mb[base];
    const int4 mk1 = *(const int4*)&mb[base + 4];
    float s = 0.f;
    s += mk0.x ? b2f((unsigned short)sv[0]) : 0.f;
    s += mk0.y ? b2f((unsigned short)sv[1]) : 0.f;
    s += mk0.z ? b2f((unsigned short)sv[2]) : 0.f;
    s += mk0.w ? b2f((unsigned short)sv[3]) : 0.f;
    s += mk1.x ? b2f((unsigned short)sv[4]) : 0.f;
    s += mk1.y ? b2f((unsigned short)sv[5]) : 0.f;
    s += mk1.z ? b2f((unsigned short)sv[6]) : 0.f;
    s += mk1.w ? b2f((unsigned short)sv[7]) : 0.f;
#pragma unroll
    for (int o = 32; o; o >>= 1) s += __shfl_xor(s, o);
    __shared__ float red[4];
    if ((t & 63) == 0) red[t >> 6] = s;
    __syncthreads();
    if (t == 0) {
        const float tot = red[0] + red[1] + red[2] + red[3];
        const float deg = mb[n] ? (tot + 1.0f) : 0.0f;
        dval[(size_t)b * 2048 + n] = rsqrtf(fmaxf(deg, 1e-6f));
    }
}

// ---------------------------------------------------------------------------
// Yt[b][d][m] = bf16( (mask[m] ? dval[m] : 0) * X[b][m][d] )  (64x64 LDS transpose)
// ---------------------------------------------------------------------------
__global__ __launch_bounds__(256)
void yt_kernel(const float* __restrict__ X, const float* __restrict__ dval,
               const int* __restrict__ mask, bf16* __restrict__ Yt)
{
    __shared__ float tile[64][65];
    const int b = blockIdx.z;
    const int m0 = blockIdx.x * 64, d0 = blockIdx.y * 64;
    const float* Xb = X + (size_t)b * 2048 * 256;
    const float* dv = dval + (size_t)b * 2048;
    const int* mk = mask + (size_t)b * 2048;
    const int t = threadIdx.x;
    const int ml = t >> 4;
    const int dl4 = (t & 15) * 4;
#pragma unroll
    for (int i = 0; i < 4; ++i) {
        const int m = ml + i * 16;
        const int gm = m0 + m;
        const float sd = mk[gm] ? dv[gm] : 0.0f;
        const float4 v = *(const float4*)&Xb[(size_t)gm * 256 + d0 + dl4];
        tile[m][dl4 + 0] = v.x * sd; tile[m][dl4 + 1] = v.y * sd;
        tile[m][dl4 + 2] = v.z * sd; tile[m][dl4 + 3] = v.w * sd;
    }
    __syncthreads();
    bf16* Yb = Yt + (size_t)b * 256 * 2048;
    const int dl = t >> 4;
    const int ml4 = (t & 15) * 4;
#pragma unroll
    for (int i = 0; i < 4; ++i) {
        const int d = dl + i * 16;
        ushort4 o;
        o.x = f2b(tile[ml4 + 0][d]);
        o.y = f2b(tile[ml4 + 1][d]);
        o.z = f2b(tile[ml4 + 2][d]);
        o.w = f2b(tile[ml4 + 3][d]);
        *(ushort4*)&Yb[(size_t)(d0 + d) * 2048 + m0 + ml4] = o;
    }
}

// ---------------------------------------------------------------------------
// Transpose both weight matrices to bf16: Wt[h][d] = bf16(W[d][h]).
// ---------------------------------------------------------------------------
__global__ __launch_bounds__(256)
void prep_w(const float* __restrict__ W1, const float* __restrict__ W2,
            bf16* __restrict__ W1t, bf16* __restrict__ W2t)
{
    const int idx = blockIdx.x * 256 + threadIdx.x;
    const int h = idx & 255, d = idx >> 8;
    W1t[h * 256 + d] = __float2bfloat16(W1[idx]);
    W2t[h * 256 + d] = __float2bfloat16(W2[idx]);
}

extern "C" void kernel_launch(void* const* d_in, const int* in_sizes, int n_in,
                              void* d_out, int out_size, void* d_ws, size_t ws_size,
                              hipStream_t stream)
{
    (void)in_sizes; (void)n_in; (void)out_size; (void)ws_size;
    const float* X  = (const float*)d_in[0];
    const int*  msk = (const int*)d_in[1];
    const float* W1 = (const float*)d_in[2];
    const float* b1 = (const float*)d_in[3];
    const float* W2 = (const float*)d_in[4];
    const float* b2 = (const float*)d_in[5];

    // scratch layout inside d_out (134,217,728 B), all dead before final GEMM:
    char* O = (char*)d_out;
    bf16* S    = (bf16*)(O);                 // 67,108,864 B  [8][2048][2048]
    bf16* Xn   = (bf16*)(O + 67108864);      //  8,388,608 B  [8][2048][256]
    bf16* Yt   = (bf16*)(O + 75497472);      //  8,388,608 B  [8][256][2048]
    bf16* agg  = (bf16*)(O + 83886080);      //  8,388,608 B  [8][2048][256]
    bf16* Hf   = (bf16*)(O + 92274688);      //  8,388,608 B  [16384][256]
    float* dvl = (float*)(O + 100663296);    //     65,536 B  [8][2048]
    bf16* W1t  = (bf16*)(O + 100728832);     //    131,072 B
    bf16* W2t  = (bf16*)(O + 100859904);     //    131,072 B
    bf16* P    = (bf16*)d_ws;                //  8,388,608 B  [16384][256] (must survive final GEMM)

    prep_w<<<256, 256, 0, stream>>>(W1, W2, W1t, W2t);
    xn_kernel<<<4096, 256, 0, stream>>>(X, Xn);

    // S = sigmoid(Xn Xn^T), bf16
    gemm_bt<0><<<dim3(16, 16, 8), 256, 0, stream>>>(
        Xn, Xn, S, 2048, 2048, 256,
        (size_t)2048 * 256, (size_t)2048 * 256, (size_t)2048 * 2048,
        nullptr, nullptr, nullptr, nullptr);

    rowsum_kernel<<<dim3(2048, 8), 256, 0, stream>>>(S, msk, dvl);
    yt_kernel<<<dim3(32, 4, 8), 256, 0, stream>>>(X, dvl, msk, Yt);

    // agg = m d (S @ Y + d X), bf16
    gemm_bt<1><<<dim3(16, 2, 8), 256, 0, stream>>>(
        S, Yt, agg, 2048, 256, 2048,
        (size_t)2048 * 2048, (size_t)256 * 2048, (size_t)2048 * 256,
        X, dvl, msk, nullptr);

    // Hf = relu(agg @ W1 + b1)
    gemm_bt<2><<<dim3(128, 2, 1), 256, 0, stream>>>(
        agg, W1t, Hf, 16384, 256, 256, 0, 0, 0,
        nullptr, nullptr, nullptr, b1);

    // P = Hf @ W2 + b2
    gemm_bt<3><<<dim3(128, 2, 1), 256, 0, stream>>>(
        Hf, W2t, P, 16384, 256, 256, 0, 0, 0,
        nullptr, nullptr, nullptr, b2);

    // out = mask_r * mask_c * sigmoid(P P^T), f32 (overwrites all scratch in d_out)
    gemm_bt<4><<<dim3(16, 16, 8), 256, 0, stream>>>(
        P, P, d_out, 2048, 2048, 256,
        (size_t)2048 * 256, (size_t)2048 * 256, (size_t)2048 * 2048,
        nullptr, nullptr, msk, nullptr);
}